// Round 10
// baseline (99.782 us; speedup 1.0000x reference)
//

#include <hip/hip_runtime.h>

// RadiusInteractionGraph: B=128 molecules x 512 atoms, K=32 NN, cutoff 10.
// d_out is FLOAT32: [E] src ++ [E] dst ++ [E] weight, E = 128*512*32.
//
// R31 = R30 (op_sel pk build, one row-pair/wave, 8192 blocks, direct-window
// compact + shared sort tail, PASS @45.3us) with the exponent search's
// SERIAL DEPTH cut 3 -> 1 rounds at EQUAL work. R30 post-mortem: conflicts
// were off the critical path (1.07M->178K changed nothing); issue utilization
// (VALU 72% + est SALU/DS) ~85% -> only depth-at-equal-work cuts remain.
// Data: 32nd-NN d2 ~ 4-7, so lo in {2,3} dominates. Test L[2]=2, L[3]=4,
// L[4]=8 SIMULTANEOUSLY (24 ballots, independent, one SALU reduce — same
// ballot count as the 3-round binary search) and resolve lo from the
// bracketing counts (monotone => exact). Rare cases: a2>=32 (dense) or
// a4<32 (sparse) take ONE more parallel round of 2 thresholds. Same lo as
// binary search in all cases; ok/fallback/repair logic untouched.
// (R23 lesson applied: depth cut must not grow per-round work.)
// Selection semantics bit-identical to lax.top_k stable order via
// key=(d2_hi23|j); exact __f*_rn np arithmetic (op_sel pk per-half IEEE RN;
// s-2*dot == s+(-2)*dot under RN); sentinel 0x7F800000|j -> pad self-edge;
// repair/fallback paths exact (R19/R26/R27 lineage).

constexpr int EDGES = 128 * 512 * 32;   // 2097152

typedef float f32x2 __attribute__((ext_vector_type(2)));

// plain packed ops (both halves independent)
static __device__ __forceinline__ f32x2 pk_mul(f32x2 a, f32x2 b) {
    f32x2 d;
    asm("v_pk_mul_f32 %0, %1, %2" : "=v"(d) : "v"(a), "v"(b));
    return d;
}
static __device__ __forceinline__ f32x2 pk_add(f32x2 a, f32x2 b) {
    f32x2 d;
    asm("v_pk_add_f32 %0, %1, %2" : "=v"(d) : "v"(a), "v"(b));
    return d;
}
// broadcast b.lo into both halves: d.lo=a.lo*b.lo, d.hi=a.hi*b.lo
static __device__ __forceinline__ f32x2 pk_mul_blo(f32x2 a, f32x2 b) {
    f32x2 d;
    asm("v_pk_mul_f32 %0, %1, %2 op_sel:[0,0] op_sel_hi:[1,0]"
        : "=v"(d) : "v"(a), "v"(b));
    return d;
}
// broadcast b.hi into both halves: d.lo=a.lo*b.hi, d.hi=a.hi*b.hi
static __device__ __forceinline__ f32x2 pk_mul_bhi(f32x2 a, f32x2 b) {
    f32x2 d;
    asm("v_pk_mul_f32 %0, %1, %2 op_sel:[0,1] op_sel_hi:[1,1]"
        : "=v"(d) : "v"(a), "v"(b));
    return d;
}
// broadcast b.hi into both halves (add)
static __device__ __forceinline__ f32x2 pk_add_bhi(f32x2 a, f32x2 b) {
    f32x2 d;
    asm("v_pk_add_f32 %0, %1, %2 op_sel:[0,1] op_sel_hi:[1,1]"
        : "=v"(d) : "v"(a), "v"(b));
    return d;
}

static __device__ __forceinline__ unsigned umin2(unsigned a, unsigned b) {
    return a < b ? a : b;
}
static __device__ __forceinline__ unsigned umax2(unsigned a, unsigned b) {
    return a > b ? a : b;
}

static __device__ __forceinline__ unsigned mbcnt64(unsigned long long m) {
    return __builtin_amdgcn_mbcnt_hi(
        (unsigned)(m >> 32),
        __builtin_amdgcn_mbcnt_lo((unsigned)m, 0u));
}

static __device__ __forceinline__ unsigned count_lt(const unsigned q[8],
                                                    unsigned C) {
    unsigned cnt = 0;
#pragma unroll
    for (int c = 0; c < 8; ++c)
        cnt += (unsigned)__popcll(__ballot(q[c] < C));
    return cnt;
}

// two-threshold parallel count (independent ballot streams)
static __device__ __forceinline__ void count_lt2(const unsigned q[8],
                                                 unsigned C0, unsigned C1,
                                                 unsigned& n0, unsigned& n1) {
    unsigned a = 0, b = 0;
#pragma unroll
    for (int c = 0; c < 8; ++c) {
        const unsigned k = q[c];
        a += (unsigned)__popcll(__ballot(k < C0));
        b += (unsigned)__popcll(__ballot(k < C1));
    }
    n0 = a; n1 = b;
}

// original greedy MSB walk over bits 30..21 (exact; rare fallback path)
static __device__ __forceinline__ unsigned full_walk(const unsigned q[8]) {
    unsigned X = 0u;
    for (int bit = 30; bit >= 21; --bit) {
        const unsigned C = X | (1u << bit);
        if (count_lt(q, C) < 32u) X = C;
    }
    return X;
}

// xor-partner fetch, all-VALU (no LDS pipe). Patterns verified (R24 PASS):
//  quad_perm 0xB1 = ^1, 0x4E = ^2, 0x1B = ^3; 0x141 row_half_mirror = ^7
//  within 8; 0x128 row_ror:8 = ^8 within 16 (+8 mod 16 == ^8).
template <int J>
static __device__ __forceinline__ unsigned xpart(unsigned v, int lane) {
    if constexpr (J == 1) {
        return (unsigned)__builtin_amdgcn_update_dpp(
            (int)v, (int)v, 0xB1, 0xF, 0xF, false);
    } else if constexpr (J == 2) {
        return (unsigned)__builtin_amdgcn_update_dpp(
            (int)v, (int)v, 0x4E, 0xF, 0xF, false);
    } else if constexpr (J == 4) {
        const int t = __builtin_amdgcn_update_dpp(
            (int)v, (int)v, 0x141, 0xF, 0xF, false);   // ^7 within 8
        return (unsigned)__builtin_amdgcn_update_dpp(
            t, t, 0x1B, 0xF, 0xF, false);              // ^3 -> net ^4
    } else if constexpr (J == 8) {
        return (unsigned)__builtin_amdgcn_update_dpp(
            (int)v, (int)v, 0x128, 0xF, 0xF, false);   // row_ror:8 = ^8
    } else if constexpr (J == 16) {
#if __has_builtin(__builtin_amdgcn_permlane16_swap)
        auto r = __builtin_amdgcn_permlane16_swap((int)v, (int)v, false, false);
        return (unsigned)((lane & 16) ? r[0] : r[1]);
#else
        return (unsigned)__shfl_xor((int)v, 16, 64);
#endif
    } else {
#if __has_builtin(__builtin_amdgcn_permlane32_swap)
        auto r = __builtin_amdgcn_permlane32_swap((int)v, (int)v, false, false);
        return (unsigned)((lane & 32) ? r[0] : r[1]);
#else
        return (unsigned)__shfl_xor((int)v, 32, 64);
#endif
    }
}

template <int K, int J>
static __device__ __forceinline__ void bstep(unsigned& v, int lane) {
    const unsigned p = xpart<J>(v, lane);
    const bool keepmin = (((lane & J) == 0) == ((lane & K) == 0));
    const unsigned mn = umin2(v, p);
    const unsigned mx = umax2(v, p);
    v = keepmin ? mn : mx;
}

// one step applied to both rows (independent chains fill stall slots;
// keepmin computed once)
template <int K, int J>
static __device__ __forceinline__ void bstep2(unsigned& a, unsigned& b,
                                              int lane) {
    const unsigned pa = xpart<J>(a, lane);
    const unsigned pb = xpart<J>(b, lane);
    const bool keepmin = (((lane & J) == 0) == ((lane & K) == 0));
    a = keepmin ? umin2(a, pa) : umax2(a, pa);
    b = keepmin ? umin2(b, pb) : umax2(b, pb);
}

// bitonic stages K=2..32 (15 steps/row), rows interleaved
static __device__ __forceinline__ void bitonic_head2(unsigned& a, unsigned& b,
                                                     int lane) {
    bstep2<2, 1>(a, b, lane);
    bstep2<4, 2>(a, b, lane);   bstep2<4, 1>(a, b, lane);
    bstep2<8, 4>(a, b, lane);   bstep2<8, 2>(a, b, lane);
    bstep2<8, 1>(a, b, lane);
    bstep2<16, 8>(a, b, lane);  bstep2<16, 4>(a, b, lane);
    bstep2<16, 2>(a, b, lane);  bstep2<16, 1>(a, b, lane);
    bstep2<32, 16>(a, b, lane); bstep2<32, 8>(a, b, lane);
    bstep2<32, 4>(a, b, lane);  bstep2<32, 2>(a, b, lane);
    bstep2<32, 1>(a, b, lane);
}

// resolve lo = largest i in [-1,6] with count(<L[i])<32 from the bracketing
// counts at i=2,3,4; rare second parallel round for dense/sparse rows.
static __device__ __forceinline__ int resolve_lo(const unsigned q[8],
                                                 unsigned n2, unsigned n3,
                                                 unsigned n4) {
    if (n2 >= 32u) {                 // dense: lo <= 1 (rare)
        unsigned n0, n1;
        count_lt2(q, 0x7Eu << 23, 0x7Fu << 23, n0, n1);
        return (n1 < 32u) ? 1 : (n0 < 32u) ? 0 : -1;
    }
    if (n4 < 32u) {                  // sparse: lo >= 4 (rare)
        unsigned n5, n6;
        count_lt2(q, 0x83u << 23, 0x84u << 23, n5, n6);
        return (n6 < 32u) ? 6 : (n5 < 32u) ? 5 : 4;
    }
    return (n3 < 32u) ? 3 : 2;       // common: one round, no recount
}

__global__ __launch_bounds__(256)
void RadiusInteractionGraph_73246372266582_kernel(const float* __restrict__ pos,
                                                  float* __restrict__ out) {
    __shared__ float4 atoms[512];        // x, y, z, |p|^2
    __shared__ unsigned wbuf[4][2][64];  // per-wave, per-row window buffer

    const int tid     = threadIdx.x;
    const int b       = blockIdx.x >> 6;          // 64 blocks per molecule
    const int rowbase = (blockIdx.x & 63) * 8;    // 8 rows per block
    const int base    = b * 512;

    for (int a = tid; a < 512; a += 256) {
        float x = pos[(base + a) * 3 + 0];
        float y = pos[(base + a) * 3 + 1];
        float z = pos[(base + a) * 3 + 2];
        // np: sum(p*p) = (x*x + y*y) + z*z, sequential f32, no fma
        float sq = __fadd_rn(__fadd_rn(__fmul_rn(x, x), __fmul_rn(y, y)),
                             __fmul_rn(z, z));
        atoms[a] = make_float4(x, y, z, sq);
    }
    __syncthreads();

    const int wave = tid >> 6;
    const int lane = tid & 63;

    const f32x2 NEG2 = {-2.0f, -2.0f};

    const int iA = rowbase + wave * 2;            // ONE row pair per wave
    const int iB = iA + 1;
    const float4 cA = atoms[iA];                  // uniform -> broadcast read
    const float4 cB = atoms[iB];
    const f32x2 CX = {cA.x, cB.x};
    const f32x2 CY = {cA.y, cB.y};
    const f32x2 CZ = {cA.z, cB.z};
    const f32x2 CW = {cA.w, cB.w};

    // ---- build 8 UNIQUE keys per lane, rows A,B packed in pk-f32;
    //      op_sel broadcasts pull pj components straight from the b128
    //      quad (no broadcast movs, single LDS read per chunk) ----
    unsigned qA[8], qB[8];
#pragma unroll
    for (int c = 0; c < 8; ++c) {
        const int j = c * 64 + lane;
        const float4 pj = atoms[j];               // one ds_read_b128
        const f32x2 pxy = {pj.x, pj.y};           // low halves of the quad
        const f32x2 pzw = {pj.z, pj.w};
        // np einsum order: ((xi*xj + yi*yj) + zi*zj), exact per half
        const f32x2 txx = pk_mul_blo(CX, pxy);    // {cA.x*xj, cB.x*xj}
        const f32x2 tyy = pk_mul_bhi(CY, pxy);    // {cA.y*yj, cB.y*yj}
        const f32x2 sxy = pk_add(txx, tyy);
        const f32x2 tzz = pk_mul_blo(CZ, pzw);    // {cA.z*zj, cB.z*zj}
        const f32x2 dot = pk_add(sxy, tzz);
        // d2 = (ci.w + pj.w) - 2*dot == (ci.w + pj.w) + (-2)*dot exactly
        const f32x2 sw  = pk_add_bhi(CW, pzw);    // {cA.w+qj, cB.w+qj}
        const f32x2 m2  = pk_mul(dot, NEG2);
        const f32x2 d2p = pk_add(sw, m2);
        const float d2A = fmaxf(d2p.x, 0.0f);
        const float d2B = fmaxf(d2p.y, 0.0f);
        qA[c] = ((j != iA) && (d2A <= 100.0f))
                    ? ((__float_as_uint(d2A) & 0xFFFFFE00u) | (unsigned)j)
                    : (0x7F800000u | (unsigned)j);
        qB[c] = ((j != iB) && (d2B <= 100.0f))
                    ? ((__float_as_uint(d2B) & 0xFFFFFE00u) | (unsigned)j)
                    : (0x7F800000u | (unsigned)j);
    }

    // ---- speculative-parallel exponent search: ONE round of 3 thresholds
    //      per row (L[2]=2.0, L[3]=4.0, L[4]=8.0; 24 ballots, independent,
    //      same total work as the old 3-round binary search), bracketing
    //      counts resolve lo exactly; rare dense/sparse rows take one more
    //      2-threshold round inside resolve_lo. ----
    const unsigned L2 = 0x80u << 23, L3 = 0x81u << 23, L4 = 0x82u << 23;
    unsigned a2 = 0, a3 = 0, a4 = 0, b2 = 0, b3 = 0, b4 = 0;
#pragma unroll
    for (int c = 0; c < 8; ++c) {
        const unsigned kA = qA[c], kB = qB[c];
        a2 += (unsigned)__popcll(__ballot(kA < L2));
        a3 += (unsigned)__popcll(__ballot(kA < L3));
        a4 += (unsigned)__popcll(__ballot(kA < L4));
        b2 += (unsigned)__popcll(__ballot(kB < L2));
        b3 += (unsigned)__popcll(__ballot(kB < L3));
        b4 += (unsigned)__popcll(__ballot(kB < L4));
    }
    const int loA = resolve_lo(qA, a2, a3, a4);
    const int loB = resolve_lo(qB, b2, b3, b4);

    // ---- window bound: common path hi = L[lo+1] (count >= 32 by
    //      definition of lo). lo outside [0,5]: exact full-walk fallback.
    const bool okA = (loA >= 0) && (loA < 6);
    const bool okB = (loB >= 0) && (loB < 6);
    unsigned hiA, hiB;
    if (okA) {
        hiA = (unsigned)((0x7F + loA) << 23);     // L[loA+1]
    } else {
        unsigned X = full_walk(qA);
        hiA = X + (1u << 21);
        if (count_lt(qA, hiA) > 64u) {            // pathological refine
            for (int bit = 20; bit >= 0; --bit) {
                const unsigned C = X | (1u << bit);
                if (count_lt(qA, C) < 32u) X = C;
            }
            hiA = X + 1u;
        }
    }
    if (okB) {
        hiB = (unsigned)((0x7F + loB) << 23);
    } else {
        unsigned X = full_walk(qB);
        hiB = X + (1u << 21);
        if (count_lt(qB, hiB) > 64u) {
            for (int bit = 20; bit >= 0; --bit) {
                const unsigned C = X | (1u << bit);
                if (count_lt(qB, C) < 32u) X = C;
            }
            hiB = X + 1u;
        }
    }

    // ---- compact (ballots -> SGPR masks, prefix, scatter); t == W ----
    unsigned long long mskA[8], mskB[8];
#pragma unroll
    for (int c = 0; c < 8; ++c) {
        mskA[c] = __ballot(qA[c] < hiA);
        mskB[c] = __ballot(qB[c] < hiB);
    }
    unsigned tA = 0, tB = 0, offA[8], offB[8];
#pragma unroll
    for (int c = 0; c < 8; ++c) {
        offA[c] = tA; tA += (unsigned)__popcll(mskA[c]);
        offB[c] = tB; tB += (unsigned)__popcll(mskB[c]);
    }
    wbuf[wave][0][lane] = 0xFFFFFFFFu;
    wbuf[wave][1][lane] = 0xFFFFFFFFu;
#pragma unroll
    for (int c = 0; c < 8; ++c) {
        if (qA[c] < hiA) wbuf[wave][0][offA[c] + mbcnt64(mskA[c])] = qA[c];
        if (qB[c] < hiB) wbuf[wave][1][offB[c] + mbcnt64(mskB[c])] = qB[c];
    }

    // ---- repair (W>64 on common path): exact mantissa+refine, redo ----
    if (okA && tA > 64u) {
        unsigned X = (unsigned)((0x7E + loA) << 23);   // L[loA], count<32
        for (int bit = 22; bit >= 21; --bit) {
            const unsigned C = X | (1u << bit);
            if (count_lt(qA, C) < 32u) X = C;
        }
        hiA = X + (1u << 21);
        if (count_lt(qA, hiA) > 64u) {
            for (int bit = 20; bit >= 0; --bit) {
                const unsigned C = X | (1u << bit);
                if (count_lt(qA, C) < 32u) X = C;
            }
            hiA = X + 1u;
        }
        wbuf[wave][0][lane] = 0xFFFFFFFFu;
        unsigned t = 0;
#pragma unroll
        for (int c = 0; c < 8; ++c) {
            const bool s = (qA[c] < hiA);
            const unsigned long long m = __ballot(s);
            if (s) wbuf[wave][0][t + mbcnt64(m)] = qA[c];
            t += (unsigned)__popcll(m);
        }
    }
    if (okB && tB > 64u) {
        unsigned X = (unsigned)((0x7E + loB) << 23);
        for (int bit = 22; bit >= 21; --bit) {
            const unsigned C = X | (1u << bit);
            if (count_lt(qB, C) < 32u) X = C;
        }
        hiB = X + (1u << 21);
        if (count_lt(qB, hiB) > 64u) {
            for (int bit = 20; bit >= 0; --bit) {
                const unsigned C = X | (1u << bit);
                if (count_lt(qB, C) < 32u) X = C;
            }
            hiB = X + 1u;
        }
        wbuf[wave][1][lane] = 0xFFFFFFFFu;
        unsigned t = 0;
#pragma unroll
        for (int c = 0; c < 8; ++c) {
            const bool s = (qB[c] < hiB);
            const unsigned long long m = __ballot(s);
            if (s) wbuf[wave][1][t + mbcnt64(m)] = qB[c];
            t += (unsigned)__popcll(m);
        }
    }

    unsigned vA = wbuf[wave][0][lane];   // per-wave LDS is in-order
    unsigned vB = wbuf[wave][1][lane];

    // ---- sort: heads + half-cleaners per row, then ONE shared tail ----
    bitonic_head2(vA, vB, lane);         // K=2..32, both rows
    bstep2<64, 32>(vA, vB, lane);        // half-cleaner: 32 smallest low
    // pack: A-low stays lanes 0-31; B-low -> lanes 32-63
    unsigned z = (lane & 32) ? xpart<32>(vB, lane) : vA;
    // final ascending merge of each bitonic 32-half; strides never cross
    // the 32-boundary and keepmin=(lane&J)==0 is correct for both halves
    bstep<64, 16>(z, lane); bstep<64, 8>(z, lane); bstep<64, 4>(z, lane);
    bstep<64, 2>(z, lane);  bstep<64, 1>(z, lane);

    // ---- epilogue: row A on lanes 0..31, row B on lanes 32..63; each
    //      of the 3 stores is a contiguous 256 B wave store.
    const int half = lane >> 5;
    const int l32  = lane & 31;
    const unsigned vv = z;
    const int gi   = iA + half;               // center atom (local idx)
    const int gdst = base + gi;
    const float4 ci = half ? cB : cA;
    float w = 0.0f;
    float srcf = (float)gdst;                 // sentinel -> self-edge, w=0
    if (vv < 0x7F800000u) {
        const int j = (int)(vv & 511u);
        const float4 pj = atoms[j];           // single random gather
        float dot = __fadd_rn(__fadd_rn(__fmul_rn(ci.x, pj.x),
                                        __fmul_rn(ci.y, pj.y)),
                              __fmul_rn(ci.z, pj.z));
        float d2 = __fsub_rn(__fadd_rn(ci.w, pj.w),
                             __fmul_rn(2.0f, dot));
        d2 = fmaxf(d2, 0.0f);
        w = __fsqrt_rn(fmaxf(d2, 1e-12f));
        srcf = (float)(base + j);
    }
    const size_t eb = (size_t)gdst * 32 + (size_t)l32;
    out[eb]                     = srcf;          // src
    out[(size_t)EDGES + eb]     = (float)gdst;   // dst
    out[(size_t)EDGES * 2 + eb] = w;             // weight
}

extern "C" void kernel_launch(void* const* d_in, const int* in_sizes, int n_in,
                              void* d_out, int out_size, void* d_ws, size_t ws_size,
                              hipStream_t stream) {
    (void)in_sizes; (void)n_in; (void)d_ws; (void)ws_size; (void)out_size;
    const float* pos = (const float*)d_in[0];   // [N,3] f32
    float* out       = (float*)d_out;           // [3E] f32

    RadiusInteractionGraph_73246372266582_kernel<<<dim3(8192), dim3(256), 0,
                                                   stream>>>(pos, out);
}

// Round 11
// 97.181 us; speedup vs baseline: 1.0268x; 1.0268x over previous
//

#include <hip/hip_runtime.h>

// RadiusInteractionGraph: B=128 molecules x 512 atoms, K=32 NN, cutoff 10.
// d_out is FLOAT32: [E] src ++ [E] dst ++ [E] weight, E = 128*512*32.
//
// R32 = REVERT to R30, the verified best (45.3us kernel / 96.5us bench).
// R31 post-mortem: speculative-parallel exponent search was ballot-equal but
// code-shape-worse (SGPR 64->112, occupancy 56->49%, 6-way accumulator
// chains broke 2-stream scheduling) -> +5us. Per the pre-committed R31
// decision rule this closes the search: R30 is the structural optimum of
// this algorithm on MI355X. Accounting at R30: VALU issue ~32.6us of
// 45.4us wall (72%), SALU ~8%, DS ~5% -> ~85% issue utilization; residual
// ~15% is barrier + drain tail (already minimized by R28's geometry).
// Not memory-bound: HBM 7.8% peak, conflicts 178K, 256B coalesced stores.
// Ladder: R21 48.2 -> R28 geometry 47.0 -> R29 mov-cut 45.4 -> R30 45.3.
//
// R30 structure: op_sel pk-f32 build (VOP3P op_sel broadcasts the pj
// component inside the instruction -> no broadcast movs, single
// ds_read_b128/chunk, classic atoms[512]={x,y,z,|p|^2} layout), one
// row-pair/wave, 8192 blocks x 256 thr, 3-round exponent binary search,
// direct-window compact (t==W) with exact post-hoc repair, shared sort
// tail (2x head K=2..32 + half-cleaner + packed final merge), dual-half
// epilogue with contiguous 256B wave stores.
// Selection semantics bit-identical to lax.top_k stable order via
// key=(d2_hi23|j); exact __f*_rn np arithmetic (op_sel pk per-half IEEE RN;
// s-2*dot == s+(-2)*dot under RN); sentinel 0x7F800000|j -> pad self-edge;
// repair/fallback paths exact (R19/R26/R27 lineage).

constexpr int EDGES = 128 * 512 * 32;   // 2097152

typedef float f32x2 __attribute__((ext_vector_type(2)));

// plain packed ops (both halves independent)
static __device__ __forceinline__ f32x2 pk_mul(f32x2 a, f32x2 b) {
    f32x2 d;
    asm("v_pk_mul_f32 %0, %1, %2" : "=v"(d) : "v"(a), "v"(b));
    return d;
}
static __device__ __forceinline__ f32x2 pk_add(f32x2 a, f32x2 b) {
    f32x2 d;
    asm("v_pk_add_f32 %0, %1, %2" : "=v"(d) : "v"(a), "v"(b));
    return d;
}
// broadcast b.lo into both halves: d.lo=a.lo*b.lo, d.hi=a.hi*b.lo
static __device__ __forceinline__ f32x2 pk_mul_blo(f32x2 a, f32x2 b) {
    f32x2 d;
    asm("v_pk_mul_f32 %0, %1, %2 op_sel:[0,0] op_sel_hi:[1,0]"
        : "=v"(d) : "v"(a), "v"(b));
    return d;
}
// broadcast b.hi into both halves: d.lo=a.lo*b.hi, d.hi=a.hi*b.hi
static __device__ __forceinline__ f32x2 pk_mul_bhi(f32x2 a, f32x2 b) {
    f32x2 d;
    asm("v_pk_mul_f32 %0, %1, %2 op_sel:[0,1] op_sel_hi:[1,1]"
        : "=v"(d) : "v"(a), "v"(b));
    return d;
}
// broadcast b.hi into both halves (add)
static __device__ __forceinline__ f32x2 pk_add_bhi(f32x2 a, f32x2 b) {
    f32x2 d;
    asm("v_pk_add_f32 %0, %1, %2 op_sel:[0,1] op_sel_hi:[1,1]"
        : "=v"(d) : "v"(a), "v"(b));
    return d;
}

static __device__ __forceinline__ unsigned umin2(unsigned a, unsigned b) {
    return a < b ? a : b;
}
static __device__ __forceinline__ unsigned umax2(unsigned a, unsigned b) {
    return a > b ? a : b;
}

static __device__ __forceinline__ unsigned mbcnt64(unsigned long long m) {
    return __builtin_amdgcn_mbcnt_hi(
        (unsigned)(m >> 32),
        __builtin_amdgcn_mbcnt_lo((unsigned)m, 0u));
}

static __device__ __forceinline__ unsigned count_lt(const unsigned q[8],
                                                    unsigned C) {
    unsigned cnt = 0;
#pragma unroll
    for (int c = 0; c < 8; ++c)
        cnt += (unsigned)__popcll(__ballot(q[c] < C));
    return cnt;
}

// original greedy MSB walk over bits 30..21 (exact; rare fallback path)
static __device__ __forceinline__ unsigned full_walk(const unsigned q[8]) {
    unsigned X = 0u;
    for (int bit = 30; bit >= 21; --bit) {
        const unsigned C = X | (1u << bit);
        if (count_lt(q, C) < 32u) X = C;
    }
    return X;
}

// xor-partner fetch, all-VALU (no LDS pipe). Patterns verified (R24 PASS):
//  quad_perm 0xB1 = ^1, 0x4E = ^2, 0x1B = ^3; 0x141 row_half_mirror = ^7
//  within 8; 0x128 row_ror:8 = ^8 within 16 (+8 mod 16 == ^8).
template <int J>
static __device__ __forceinline__ unsigned xpart(unsigned v, int lane) {
    if constexpr (J == 1) {
        return (unsigned)__builtin_amdgcn_update_dpp(
            (int)v, (int)v, 0xB1, 0xF, 0xF, false);
    } else if constexpr (J == 2) {
        return (unsigned)__builtin_amdgcn_update_dpp(
            (int)v, (int)v, 0x4E, 0xF, 0xF, false);
    } else if constexpr (J == 4) {
        const int t = __builtin_amdgcn_update_dpp(
            (int)v, (int)v, 0x141, 0xF, 0xF, false);   // ^7 within 8
        return (unsigned)__builtin_amdgcn_update_dpp(
            t, t, 0x1B, 0xF, 0xF, false);              // ^3 -> net ^4
    } else if constexpr (J == 8) {
        return (unsigned)__builtin_amdgcn_update_dpp(
            (int)v, (int)v, 0x128, 0xF, 0xF, false);   // row_ror:8 = ^8
    } else if constexpr (J == 16) {
#if __has_builtin(__builtin_amdgcn_permlane16_swap)
        auto r = __builtin_amdgcn_permlane16_swap((int)v, (int)v, false, false);
        return (unsigned)((lane & 16) ? r[0] : r[1]);
#else
        return (unsigned)__shfl_xor((int)v, 16, 64);
#endif
    } else {
#if __has_builtin(__builtin_amdgcn_permlane32_swap)
        auto r = __builtin_amdgcn_permlane32_swap((int)v, (int)v, false, false);
        return (unsigned)((lane & 32) ? r[0] : r[1]);
#else
        return (unsigned)__shfl_xor((int)v, 32, 64);
#endif
    }
}

template <int K, int J>
static __device__ __forceinline__ void bstep(unsigned& v, int lane) {
    const unsigned p = xpart<J>(v, lane);
    const bool keepmin = (((lane & J) == 0) == ((lane & K) == 0));
    const unsigned mn = umin2(v, p);
    const unsigned mx = umax2(v, p);
    v = keepmin ? mn : mx;
}

// one step applied to both rows (independent chains fill stall slots;
// keepmin computed once)
template <int K, int J>
static __device__ __forceinline__ void bstep2(unsigned& a, unsigned& b,
                                              int lane) {
    const unsigned pa = xpart<J>(a, lane);
    const unsigned pb = xpart<J>(b, lane);
    const bool keepmin = (((lane & J) == 0) == ((lane & K) == 0));
    a = keepmin ? umin2(a, pa) : umax2(a, pa);
    b = keepmin ? umin2(b, pb) : umax2(b, pb);
}

// bitonic stages K=2..32 (15 steps/row), rows interleaved
static __device__ __forceinline__ void bitonic_head2(unsigned& a, unsigned& b,
                                                     int lane) {
    bstep2<2, 1>(a, b, lane);
    bstep2<4, 2>(a, b, lane);   bstep2<4, 1>(a, b, lane);
    bstep2<8, 4>(a, b, lane);   bstep2<8, 2>(a, b, lane);
    bstep2<8, 1>(a, b, lane);
    bstep2<16, 8>(a, b, lane);  bstep2<16, 4>(a, b, lane);
    bstep2<16, 2>(a, b, lane);  bstep2<16, 1>(a, b, lane);
    bstep2<32, 16>(a, b, lane); bstep2<32, 8>(a, b, lane);
    bstep2<32, 4>(a, b, lane);  bstep2<32, 2>(a, b, lane);
    bstep2<32, 1>(a, b, lane);
}

__global__ __launch_bounds__(256)
void RadiusInteractionGraph_73246372266582_kernel(const float* __restrict__ pos,
                                                  float* __restrict__ out) {
    __shared__ float4 atoms[512];        // x, y, z, |p|^2
    __shared__ unsigned wbuf[4][2][64];  // per-wave, per-row window buffer

    const int tid     = threadIdx.x;
    const int b       = blockIdx.x >> 6;          // 64 blocks per molecule
    const int rowbase = (blockIdx.x & 63) * 8;    // 8 rows per block
    const int base    = b * 512;

    for (int a = tid; a < 512; a += 256) {
        float x = pos[(base + a) * 3 + 0];
        float y = pos[(base + a) * 3 + 1];
        float z = pos[(base + a) * 3 + 2];
        // np: sum(p*p) = (x*x + y*y) + z*z, sequential f32, no fma
        float sq = __fadd_rn(__fadd_rn(__fmul_rn(x, x), __fmul_rn(y, y)),
                             __fmul_rn(z, z));
        atoms[a] = make_float4(x, y, z, sq);
    }
    __syncthreads();

    const int wave = tid >> 6;
    const int lane = tid & 63;

    const f32x2 NEG2 = {-2.0f, -2.0f};

    const int iA = rowbase + wave * 2;            // ONE row pair per wave
    const int iB = iA + 1;
    const float4 cA = atoms[iA];                  // uniform -> broadcast read
    const float4 cB = atoms[iB];
    const f32x2 CX = {cA.x, cB.x};
    const f32x2 CY = {cA.y, cB.y};
    const f32x2 CZ = {cA.z, cB.z};
    const f32x2 CW = {cA.w, cB.w};

    // ---- build 8 UNIQUE keys per lane, rows A,B packed in pk-f32;
    //      op_sel broadcasts pull pj components straight from the b128
    //      quad (no broadcast movs, single LDS read per chunk) ----
    unsigned qA[8], qB[8];
#pragma unroll
    for (int c = 0; c < 8; ++c) {
        const int j = c * 64 + lane;
        const float4 pj = atoms[j];               // one ds_read_b128
        const f32x2 pxy = {pj.x, pj.y};           // low halves of the quad
        const f32x2 pzw = {pj.z, pj.w};
        // np einsum order: ((xi*xj + yi*yj) + zi*zj), exact per half
        const f32x2 txx = pk_mul_blo(CX, pxy);    // {cA.x*xj, cB.x*xj}
        const f32x2 tyy = pk_mul_bhi(CY, pxy);    // {cA.y*yj, cB.y*yj}
        const f32x2 sxy = pk_add(txx, tyy);
        const f32x2 tzz = pk_mul_blo(CZ, pzw);    // {cA.z*zj, cB.z*zj}
        const f32x2 dot = pk_add(sxy, tzz);
        // d2 = (ci.w + pj.w) - 2*dot == (ci.w + pj.w) + (-2)*dot exactly
        const f32x2 sw  = pk_add_bhi(CW, pzw);    // {cA.w+qj, cB.w+qj}
        const f32x2 m2  = pk_mul(dot, NEG2);
        const f32x2 d2p = pk_add(sw, m2);
        const float d2A = fmaxf(d2p.x, 0.0f);
        const float d2B = fmaxf(d2p.y, 0.0f);
        qA[c] = ((j != iA) && (d2A <= 100.0f))
                    ? ((__float_as_uint(d2A) & 0xFFFFFE00u) | (unsigned)j)
                    : (0x7F800000u | (unsigned)j);
        qB[c] = ((j != iB) && (d2B <= 100.0f))
                    ? ((__float_as_uint(d2B) & 0xFFFFFE00u) | (unsigned)j)
                    : (0x7F800000u | (unsigned)j);
    }

    // ---- exponent binary search: 3 rounds over L[i]=(0x7E+i)<<23 ----
    // (d2 thresholds 0.5,1,2,4,8,16,32). Largest i with count(<L[i])<32.
    int loA = -1, hiiA = 7, loB = -1, hiiB = 7;
#pragma unroll
    for (int r = 0; r < 3; ++r) {
        const int mA = (loA + hiiA) >> 1;
        const int mB = (loB + hiiB) >> 1;
        const unsigned CA = (unsigned)((0x7E + mA) << 23);
        const unsigned CB = (unsigned)((0x7E + mB) << 23);
        unsigned ca = 0, cb = 0;
#pragma unroll
        for (int c = 0; c < 8; ++c) {
            ca += (unsigned)__popcll(__ballot(qA[c] < CA));
            cb += (unsigned)__popcll(__ballot(qB[c] < CB));
        }
        if (ca < 32u) loA = mA; else hiiA = mA;
        if (cb < 32u) loB = mB; else hiiB = mB;
    }

    // ---- window bound: common path hi = L[lo+1] (tested-rejected =>
    //      count >= 32). lo outside [0,5]: exact full-walk fallback.
    const bool okA = (loA >= 0) && (loA < 6);
    const bool okB = (loB >= 0) && (loB < 6);
    unsigned hiA, hiB;
    if (okA) {
        hiA = (unsigned)((0x7F + loA) << 23);     // L[loA+1]
    } else {
        unsigned X = full_walk(qA);
        hiA = X + (1u << 21);
        if (count_lt(qA, hiA) > 64u) {            // pathological refine
            for (int bit = 20; bit >= 0; --bit) {
                const unsigned C = X | (1u << bit);
                if (count_lt(qA, C) < 32u) X = C;
            }
            hiA = X + 1u;
        }
    }
    if (okB) {
        hiB = (unsigned)((0x7F + loB) << 23);
    } else {
        unsigned X = full_walk(qB);
        hiB = X + (1u << 21);
        if (count_lt(qB, hiB) > 64u) {
            for (int bit = 20; bit >= 0; --bit) {
                const unsigned C = X | (1u << bit);
                if (count_lt(qB, C) < 32u) X = C;
            }
            hiB = X + 1u;
        }
    }

    // ---- compact (ballots -> SGPR masks, prefix, scatter); t == W ----
    unsigned long long mskA[8], mskB[8];
#pragma unroll
    for (int c = 0; c < 8; ++c) {
        mskA[c] = __ballot(qA[c] < hiA);
        mskB[c] = __ballot(qB[c] < hiB);
    }
    unsigned tA = 0, tB = 0, offA[8], offB[8];
#pragma unroll
    for (int c = 0; c < 8; ++c) {
        offA[c] = tA; tA += (unsigned)__popcll(mskA[c]);
        offB[c] = tB; tB += (unsigned)__popcll(mskB[c]);
    }
    wbuf[wave][0][lane] = 0xFFFFFFFFu;
    wbuf[wave][1][lane] = 0xFFFFFFFFu;
#pragma unroll
    for (int c = 0; c < 8; ++c) {
        if (qA[c] < hiA) wbuf[wave][0][offA[c] + mbcnt64(mskA[c])] = qA[c];
        if (qB[c] < hiB) wbuf[wave][1][offB[c] + mbcnt64(mskB[c])] = qB[c];
    }

    // ---- repair (W>64 on common path): exact mantissa+refine, redo ----
    if (okA && tA > 64u) {
        unsigned X = (unsigned)((0x7E + loA) << 23);   // L[loA], count<32
        for (int bit = 22; bit >= 21; --bit) {
            const unsigned C = X | (1u << bit);
            if (count_lt(qA, C) < 32u) X = C;
        }
        hiA = X + (1u << 21);
        if (count_lt(qA, hiA) > 64u) {
            for (int bit = 20; bit >= 0; --bit) {
                const unsigned C = X | (1u << bit);
                if (count_lt(qA, C) < 32u) X = C;
            }
            hiA = X + 1u;
        }
        wbuf[wave][0][lane] = 0xFFFFFFFFu;
        unsigned t = 0;
#pragma unroll
        for (int c = 0; c < 8; ++c) {
            const bool s = (qA[c] < hiA);
            const unsigned long long m = __ballot(s);
            if (s) wbuf[wave][0][t + mbcnt64(m)] = qA[c];
            t += (unsigned)__popcll(m);
        }
    }
    if (okB && tB > 64u) {
        unsigned X = (unsigned)((0x7E + loB) << 23);
        for (int bit = 22; bit >= 21; --bit) {
            const unsigned C = X | (1u << bit);
            if (count_lt(qB, C) < 32u) X = C;
        }
        hiB = X + (1u << 21);
        if (count_lt(qB, hiB) > 64u) {
            for (int bit = 20; bit >= 0; --bit) {
                const unsigned C = X | (1u << bit);
                if (count_lt(qB, C) < 32u) X = C;
            }
            hiB = X + 1u;
        }
        wbuf[wave][1][lane] = 0xFFFFFFFFu;
        unsigned t = 0;
#pragma unroll
        for (int c = 0; c < 8; ++c) {
            const bool s = (qB[c] < hiB);
            const unsigned long long m = __ballot(s);
            if (s) wbuf[wave][1][t + mbcnt64(m)] = qB[c];
            t += (unsigned)__popcll(m);
        }
    }

    unsigned vA = wbuf[wave][0][lane];   // per-wave LDS is in-order
    unsigned vB = wbuf[wave][1][lane];

    // ---- sort: heads + half-cleaners per row, then ONE shared tail ----
    bitonic_head2(vA, vB, lane);         // K=2..32, both rows
    bstep2<64, 32>(vA, vB, lane);        // half-cleaner: 32 smallest low
    // pack: A-low stays lanes 0-31; B-low -> lanes 32-63
    unsigned z = (lane & 32) ? xpart<32>(vB, lane) : vA;
    // final ascending merge of each bitonic 32-half; strides never cross
    // the 32-boundary and keepmin=(lane&J)==0 is correct for both halves
    bstep<64, 16>(z, lane); bstep<64, 8>(z, lane); bstep<64, 4>(z, lane);
    bstep<64, 2>(z, lane);  bstep<64, 1>(z, lane);

    // ---- epilogue: row A on lanes 0..31, row B on lanes 32..63; each
    //      of the 3 stores is a contiguous 256 B wave store.
    const int half = lane >> 5;
    const int l32  = lane & 31;
    const unsigned vv = z;
    const int gi   = iA + half;               // center atom (local idx)
    const int gdst = base + gi;
    const float4 ci = half ? cB : cA;
    float w = 0.0f;
    float srcf = (float)gdst;                 // sentinel -> self-edge, w=0
    if (vv < 0x7F800000u) {
        const int j = (int)(vv & 511u);
        const float4 pj = atoms[j];           // single random gather
        float dot = __fadd_rn(__fadd_rn(__fmul_rn(ci.x, pj.x),
                                        __fmul_rn(ci.y, pj.y)),
                              __fmul_rn(ci.z, pj.z));
        float d2 = __fsub_rn(__fadd_rn(ci.w, pj.w),
                             __fmul_rn(2.0f, dot));
        d2 = fmaxf(d2, 0.0f);
        w = __fsqrt_rn(fmaxf(d2, 1e-12f));
        srcf = (float)(base + j);
    }
    const size_t eb = (size_t)gdst * 32 + (size_t)l32;
    out[eb]                     = srcf;          // src
    out[(size_t)EDGES + eb]     = (float)gdst;   // dst
    out[(size_t)EDGES * 2 + eb] = w;             // weight
}

extern "C" void kernel_launch(void* const* d_in, const int* in_sizes, int n_in,
                              void* d_out, int out_size, void* d_ws, size_t ws_size,
                              hipStream_t stream) {
    (void)in_sizes; (void)n_in; (void)d_ws; (void)ws_size; (void)out_size;
    const float* pos = (const float*)d_in[0];   // [N,3] f32
    float* out       = (float*)d_out;           // [3E] f32

    RadiusInteractionGraph_73246372266582_kernel<<<dim3(8192), dim3(256), 0,
                                                   stream>>>(pos, out);
}